// Round 14
// baseline (83.579 us; speedup 1.0000x reference)
//
#include <hip/hip_runtime.h>
#include <hip/hip_bf16.h>

#define B_     32
#define N_     16384
#define D_     64
#define C_     36
#define CP_    48     // padded cluster count (3 x 16 MFMA tiles)
#define FG_    32
#define ALPHA_ 10.0f
#define NB_    64     // n-blocks per batch -> grid 2048 -> 5 blocks/CU resident
#define RPB_   (N_/NB_)   // 256 rows per block
#define PIT_   70         // LDS row pitch: 140 B; dword stride 35 (odd) ->
                          // ws-GEMM b64 reads spread odd+even banks, <=2-way

typedef __attribute__((ext_vector_type(8))) short bf16x8;
typedef __attribute__((ext_vector_type(4))) short bf16x4;
typedef __attribute__((ext_vector_type(4))) float f32x4;

#define MFMA(a,b,c) __builtin_amdgcn_mfma_f32_16x16x32_bf16(a,b,c,0,0,0)

// float -> bf16 bits via native conversion (v_cvt_pk_bf16_f32, RNE on gfx950).
__device__ __forceinline__ short bfbits(float v){
  __bf16 h = (__bf16)v;
  return __builtin_bit_cast(short, h);
}
__device__ __forceinline__ float bfval(short u){
  return __uint_as_float(((unsigned)(unsigned short)u) << 16);
}

// v -> hi bf16 (slot J of H) + residual lo bf16 (slot J of L)
#define CVT1(v, H, L, J) { short hb_ = bfbits(v); (H)[J] = hb_; \
  (L)[J] = bfbits((v) - bfval(hb_)); }

__device__ __forceinline__ bf16x8 ld_frag(const unsigned short* p){
  bf16x4 a = *(const bf16x4*)p;
  bf16x4 b = *(const bf16x4*)(p + 4);
  return __builtin_shufflevector(a, b, 0,1,2,3,4,5,6,7);
}

// ---------------------------------------------------------------------------
// Cooperative-block kernel. grid = 2048 (32 batches x 64 n-blocks),
// block = 256 = 4 waves. Block processes 4 units of 64 rows; per unit each
// wave computes cos+softmax for its OWN 16 rows (row = 16*wid + lm) into a
// DOUBLE-BUFFERED shared asg/xt pair, then ws-GEMMs all 64 rows against its
// PRIVATE 16-wide d-tile (d = 16*wid + lm). One __syncthreads per unit
// (round-12 proven; round-13's inline-asm barrier + sched_barrier regressed
// per m141 order-pinning). Registers ~92 combined + LDS 31.4 KB -> 5
// blocks/CU resident with grid 2048 (was grid-capped at 4).
// self_product recovered in k_red1 via identity sp[c] = sum_d cn[d,c]*ws[d,c].
// ---------------------------------------------------------------------------
template<int NPART>
__global__ __launch_bounds__(256, 2) void k_accum(
    const float* __restrict__ x, const float* __restrict__ cent,
    float* __restrict__ wsP)
{
  const int t   = threadIdx.x;
  const int wid = t >> 6;
  const int l   = t & 63;
  const int lm  = l & 15;
  const int lg  = l >> 4;
  const int b   = blockIdx.x >> 6;
  const int nb  = blockIdx.x & 63;

  __shared__ float nrmc[C_];
  __shared__ __align__(16) unsigned short aw0[CP_*PIT_];  // asg buf 0  6720 B
  __shared__ __align__(16) unsigned short xw0[D_*PIT_];   // xt  buf 0  8960 B
  __shared__ __align__(16) unsigned short aw1[CP_*PIT_];  // asg buf 1
  __shared__ __align__(16) unsigned short xw1[D_*PIT_];   // xt  buf 1

  if (t < C_) {
    float ss = 0.f;
    for (int d = 0; d < D_; ++d) { float v = cent[d*C_ + t]; ss = fmaf(v, v, ss); }
    nrmc[t] = rsqrtf(fmaxf(ss, 1e-24f));
  }
  __syncthreads();

  // normalized-centroid A-fragments: A[m=c][k=d], c = 16*ct+lm, d = 32*s+8*lg+j
  bf16x8 cnf[3][2];
  #pragma unroll
  for (int ct = 0; ct < 3; ++ct) {
    #pragma unroll
    for (int s = 0; s < 2; ++s) {
      bf16x8 f;
      #pragma unroll
      for (int j = 0; j < 8; ++j) {
        int d = 32*s + 8*lg + j;
        int c = 16*ct + lm;
        float v = (c < C_) ? cent[d*C_ + c] * nrmc[c] : 0.f;
        f[j] = bfbits(v);
      }
      cnf[ct][s] = f;
    }
  }

  f32x4 acc[3];                      // wave's output: [c 48][d-tile wid 16]
  acc[0] = (f32x4){0.f,0.f,0.f,0.f};
  acc[1] = (f32x4){0.f,0.f,0.f,0.f};
  acc[2] = (f32x4){0.f,0.f,0.f,0.f};

  const int rowin = 16*wid + lm;     // this lane's row within the 64-row unit

  // per-unit staging: lane holds row rowin, float cols {8lg..+7, 32+8lg..+7}
  auto process = [&](float4 c0, float4 c1, float4 c2, float4 c3,
                     unsigned short* aw, unsigned short* xw) {
    float ss = 0.f;
    ss = fmaf(c0.x,c0.x,ss); ss = fmaf(c0.y,c0.y,ss); ss = fmaf(c0.z,c0.z,ss); ss = fmaf(c0.w,c0.w,ss);
    ss = fmaf(c1.x,c1.x,ss); ss = fmaf(c1.y,c1.y,ss); ss = fmaf(c1.z,c1.z,ss); ss = fmaf(c1.w,c1.w,ss);
    ss = fmaf(c2.x,c2.x,ss); ss = fmaf(c2.y,c2.y,ss); ss = fmaf(c2.z,c2.z,ss); ss = fmaf(c2.w,c2.w,ss);
    ss = fmaf(c3.x,c3.x,ss); ss = fmaf(c3.y,c3.y,ss); ss = fmaf(c3.z,c3.z,ss); ss = fmaf(c3.w,c3.w,ss);
    ss += __shfl_xor(ss, 16);
    ss += __shfl_xor(ss, 32);
    float rn = rsqrtf(fmaxf(ss, 1e-24f));

    bf16x8 bh0, bl0, bh1, bl1;
    CVT1(c0.x,bh0,bl0,0) CVT1(c0.y,bh0,bl0,1) CVT1(c0.z,bh0,bl0,2) CVT1(c0.w,bh0,bl0,3)
    CVT1(c1.x,bh0,bl0,4) CVT1(c1.y,bh0,bl0,5) CVT1(c1.z,bh0,bl0,6) CVT1(c1.w,bh0,bl0,7)
    CVT1(c2.x,bh1,bl1,0) CVT1(c2.y,bh1,bl1,1) CVT1(c2.z,bh1,bl1,2) CVT1(c2.w,bh1,bl1,3)
    CVT1(c3.x,bh1,bl1,4) CVT1(c3.y,bh1,bl1,5) CVT1(c3.z,bh1,bl1,6) CVT1(c3.w,bh1,bl1,7)

    // cos GEMM: D[m=c][n=row] = cn . x (raw x; rn applied in softmax arg)
    f32x4 q0 = (f32x4){0,0,0,0}, q1 = (f32x4){0,0,0,0}, q2 = (f32x4){0,0,0,0};
    q0 = MFMA(cnf[0][0], bh0, q0); q0 = MFMA(cnf[0][1], bh1, q0);
    q0 = MFMA(cnf[0][0], bl0, q0); q0 = MFMA(cnf[0][1], bl1, q0);
    q1 = MFMA(cnf[1][0], bh0, q1); q1 = MFMA(cnf[1][1], bh1, q1);
    q1 = MFMA(cnf[1][0], bl0, q1); q1 = MFMA(cnf[1][1], bl1, q1);
    q2 = MFMA(cnf[2][0], bh0, q2); q2 = MFMA(cnf[2][1], bh1, q2);
    q2 = MFMA(cnf[2][0], bl0, q2); q2 = MFMA(cnf[2][1], bl1, q2);
    f32x4 q[3] = {q0, q1, q2};

    // softmax over c; lane holds c = 16ct+4lg+r for its row (n-col = lm)
    float e[3][4]; float psum = 0.f;
    #pragma unroll
    for (int ct = 0; ct < 3; ++ct)
      #pragma unroll
      for (int r = 0; r < 4; ++r) {
        int c = 16*ct + 4*lg + r;
        float ev = (c < C_) ? __expf(ALPHA_ * rn * q[ct][r]) : 0.f;
        e[ct][r] = ev; psum += ev;
      }
    psum += __shfl_xor(psum, 16);
    psum += __shfl_xor(psum, 32);
    float arn = rn / psum;               // (assign * rn) scale

    #pragma unroll
    for (int ct = 0; ct < 3; ++ct)
      #pragma unroll
      for (int r = 0; r < 4; ++r)
        aw[(16*ct + 4*lg + r)*PIT_ + rowin] = (unsigned short)bfbits(e[ct][r] * arn);
    #pragma unroll
    for (int j = 0; j < 8; ++j) {
      xw[(     8*lg + j)*PIT_ + rowin] = (unsigned short)bh0[j];   // xt[d][row]
      xw[(32 + 8*lg + j)*PIT_ + rowin] = (unsigned short)bh1[j];
    }
  };

  // ws GEMM over the unit's 64 rows for this wave's d-tile (d = 16*wid+lm)
  auto wsgemm = [&](const unsigned short* aw, const unsigned short* xw) {
    #pragma unroll
    for (int s = 0; s < 2; ++s) {                      // k = rows 32s..32s+31
      bf16x8 xf = ld_frag(&xw[(16*wid + lm)*PIT_ + 32*s + 8*lg]);
      bf16x8 a0 = ld_frag(&aw[( 0 + lm)*PIT_ + 32*s + 8*lg]);
      bf16x8 a1 = ld_frag(&aw[(16 + lm)*PIT_ + 32*s + 8*lg]);
      bf16x8 a2 = ld_frag(&aw[(32 + lm)*PIT_ + 32*s + 8*lg]);
      acc[0] = MFMA(a0, xf, acc[0]);
      acc[1] = MFMA(a1, xf, acc[1]);
      acc[2] = MFMA(a2, xf, acc[2]);
    }
  };

  // lane's global base: its row (16*wid+lm) of unit 0; units stride 64 rows
  const float* px = x + ((size_t)b*N_ + (size_t)nb*RPB_ + rowin)*D_ + lg*8;

  #define LOADU(P0,P1,P2,P3,U) { const float* p_ = px + (size_t)(U)*4096; \
    P0=*(const float4*)p_; P1=*(const float4*)(p_+4); P2=*(const float4*)(p_+32); P3=*(const float4*)(p_+36); }

  float4 A0,A1,A2,A3, B0,B1,B2,B3;
  LOADU(A0,A1,A2,A3, 0)
  LOADU(B0,B1,B2,B3, 1)

  #pragma unroll
  for (int u = 0; u < 4; u += 2) {
    process(A0,A1,A2,A3, aw0, xw0);          // unit u -> buf 0
    if (u < 2) LOADU(A0,A1,A2,A3, u+2)
    __syncthreads();                         // buf0 writes visible
    wsgemm(aw0, xw0);

    process(B0,B1,B2,B3, aw1, xw1);          // unit u+1 -> buf 1
    if (u < 2) LOADU(B0,B1,B2,B3, u+3)
    __syncthreads();                         // buf1 visible; also fences buf0
    wsgemm(aw1, xw1);                        //   reads before next buf0 write
  }
  #undef LOADU

  // ---- epilogue: disjoint output tiles -> plain stores, no reduction ----
  if (NPART == NB_) {
    float* wp = wsP + (size_t)blockIdx.x*(C_*D_) + 16*wid + lm;  // d = 16wid+lm
    #pragma unroll
    for (int ct = 0; ct < 3; ++ct)
      #pragma unroll
      for (int r = 0; r < 4; ++r) {
        int c = 16*ct + 4*lg + r;
        if (c < C_) wp[c*D_] = acc[ct][r];
      }
  } else {
    float* wp = wsP + (size_t)b*(C_*D_) + 16*wid + lm;
    #pragma unroll
    for (int ct = 0; ct < 3; ++ct)
      #pragma unroll
      for (int r = 0; r < 4; ++r) {
        int c = 16*ct + 4*lg + r;
        if (c < C_) atomicAdd(&wp[c*D_], acc[ct][r]);
      }
  }
}

// ---------------------------------------------------------------------------
// Reduce + finalize: grid = B_*FG_ (1024) x 256 threads; 4 k-quarters
// (16 partials each at NPART=64) reduced via LDS. sp via identity;
// global norm analytic (all C_ rows unit-norm => ||flat|| = sqrt(C_)).
// ---------------------------------------------------------------------------
template<int NPART>
__global__ __launch_bounds__(256) void k_red1(
    const float* __restrict__ cent, const float* __restrict__ wsP,
    float* __restrict__ out)
{
  const int bc = blockIdx.x;
  const int b  = bc >> 5;        // / FG_
  const int c  = bc & 31;        // % FG_
  const int t  = threadIdx.x;
  const int d  = t & 63;
  const int kq = t >> 6;         // k-quarter

  __shared__ float pr[4][64];

  float s = 0.f;
  for (int k = kq; k < NPART; k += 4)
    s += wsP[((size_t)b*NPART + k)*(C_*D_) + c*D_ + d];
  pr[kq][d] = s;
  __syncthreads();

  if (t < 64) {
    s = pr[0][d] + pr[1][d] + pr[2][d] + pr[3][d];

    float cv = cent[d*C_ + c];
    float cs = cv*cv;
    #pragma unroll
    for (int off = 32; off; off >>= 1) cs += __shfl_xor(cs, off);
    float cn = cv * rsqrtf(fmaxf(cs, 1e-24f));

    float spv = cn * s;
    #pragma unroll
    for (int off = 32; off; off >>= 1) spv += __shfl_xor(spv, off);

    float v = s - cn * spv;
    float vs = v*v;
    #pragma unroll
    for (int off = 32; off; off >>= 1) vs += __shfl_xor(vs, off);

    const float rg = 0.16666666666666666f;   // 1/sqrt(C_)
    out[(size_t)bc*D_ + d] = v * rsqrtf(fmaxf(vs, 1e-24f)) * rg;
  }
}

extern "C" void kernel_launch(void* const* d_in, const int* in_sizes, int n_in,
                              void* d_out, int out_size, void* d_ws, size_t ws_size,
                              hipStream_t stream) {
  const float* x    = (const float*)d_in[0];
  const float* cent = (const float*)d_in[1];
  float* out = (float*)d_out;

  const size_t nblk = (size_t)B_ * NB_;                 // 2048
  const size_t need = nblk*(C_*D_) * sizeof(float);     // ~18.9 MB

  if (ws_size >= need) {
    float* wsP = (float*)d_ws;                          // [2048][2304]
    k_accum<NB_><<<B_*NB_, 256, 0, stream>>>(x, cent, wsP);
    k_red1<NB_><<<B_*FG_, 256, 0, stream>>>(cent, wsP, out);
  } else {                                              // atomic fallback
    float* wsA = (float*)d_ws;                          // [32][2304]
    hipMemsetAsync(d_ws, 0, (size_t)B_*(C_*D_)*sizeof(float), stream);
    k_accum<1><<<B_*NB_, 256, 0, stream>>>(x, cent, wsA);
    k_red1<1><<<B_*FG_, 256, 0, stream>>>(cent, wsA, out);
  }
}

// Round 15
// 80.179 us; speedup vs baseline: 1.0424x; 1.0424x over previous
//
#include <hip/hip_runtime.h>
#include <hip/hip_bf16.h>

#define B_     32
#define N_     16384
#define D_     64
#define C_     36
#define CP_    48     // padded cluster count (3 x 16 MFMA tiles)
#define FG_    32
#define ALPHA_ 10.0f
#define NB_    32     // n-blocks per batch -> grid 1024 = 4 blocks/CU
#define RPB_   (N_/NB_)   // 512 rows per block
#define PIT_   70         // LDS row pitch: 140 B (odd dword stride 35) ->
                          // ws-GEMM b64 reads conflict-free (r14: SQ_LDS_BANK_CONFLICT=0)

typedef __attribute__((ext_vector_type(8))) short bf16x8;
typedef __attribute__((ext_vector_type(4))) short bf16x4;
typedef __attribute__((ext_vector_type(4))) float f32x4;

#define MFMA(a,b,c) __builtin_amdgcn_mfma_f32_16x16x32_bf16(a,b,c,0,0,0)

// float -> bf16 bits via native conversion (v_cvt_pk_bf16_f32, RNE on gfx950).
__device__ __forceinline__ short bfbits(float v){
  __bf16 h = (__bf16)v;
  return __builtin_bit_cast(short, h);
}
__device__ __forceinline__ float bfval(short u){
  return __uint_as_float(((unsigned)(unsigned short)u) << 16);
}

// v -> hi bf16 (slot J of H) + residual lo bf16 (slot J of L)
#define CVT1(v, H, L, J) { short hb_ = bfbits(v); (H)[J] = hb_; \
  (L)[J] = bfbits((v) - bfval(hb_)); }

__device__ __forceinline__ bf16x8 ld_frag(const unsigned short* p){
  bf16x4 a = *(const bf16x4*)p;
  bf16x4 b = *(const bf16x4*)(p + 4);
  return __builtin_shufflevector(a, b, 0,1,2,3,4,5,6,7);
}

// ---------------------------------------------------------------------------
// Cooperative-block kernel (round-12 structure, PIT 68->70 only change).
// grid = 1024 (32 batches x 32 n-blocks), block = 256 = 4 waves.
// Block processes 8 units of 64 rows; per unit each wave computes cos+softmax
// for its OWN 16 rows (row = 16*wid + lm) into a DOUBLE-BUFFERED shared
// asg/xt pair, then ws-GEMMs all 64 rows against its PRIVATE 16-wide d-tile
// (d = 16*wid + lm). One __syncthreads per unit. acc = 3 f32x4 (12 AGPRs).
// Codegen-stability notes: 8-unit loop + grid 1024 is the allocator's stable
// point (4-unit loop [r14] and (256,4) bounds [r9] flip to a 60-64 VGPR
// spilling allocation; 2.2-4x regressions). No device-scope fences (r10).
// self_product recovered in k_red1 via identity sp[c] = sum_d cn[d,c]*ws[d,c].
// ---------------------------------------------------------------------------
template<int NPART>
__global__ __launch_bounds__(256, 2) void k_accum(
    const float* __restrict__ x, const float* __restrict__ cent,
    float* __restrict__ wsP)
{
  const int t   = threadIdx.x;
  const int wid = t >> 6;
  const int l   = t & 63;
  const int lm  = l & 15;
  const int lg  = l >> 4;
  const int b   = blockIdx.x >> 5;
  const int nb  = blockIdx.x & 31;

  __shared__ float nrmc[C_];
  __shared__ __align__(16) unsigned short aw0[CP_*PIT_];  // asg buf 0  6720 B
  __shared__ __align__(16) unsigned short xw0[D_*PIT_];   // xt  buf 0  8960 B
  __shared__ __align__(16) unsigned short aw1[CP_*PIT_];  // asg buf 1
  __shared__ __align__(16) unsigned short xw1[D_*PIT_];   // xt  buf 1

  if (t < C_) {
    float ss = 0.f;
    for (int d = 0; d < D_; ++d) { float v = cent[d*C_ + t]; ss = fmaf(v, v, ss); }
    nrmc[t] = rsqrtf(fmaxf(ss, 1e-24f));
  }
  __syncthreads();

  // normalized-centroid A-fragments: A[m=c][k=d], c = 16*ct+lm, d = 32*s+8*lg+j
  bf16x8 cnf[3][2];
  #pragma unroll
  for (int ct = 0; ct < 3; ++ct) {
    #pragma unroll
    for (int s = 0; s < 2; ++s) {
      bf16x8 f;
      #pragma unroll
      for (int j = 0; j < 8; ++j) {
        int d = 32*s + 8*lg + j;
        int c = 16*ct + lm;
        float v = (c < C_) ? cent[d*C_ + c] * nrmc[c] : 0.f;
        f[j] = bfbits(v);
      }
      cnf[ct][s] = f;
    }
  }

  f32x4 acc[3];                      // wave's output: [c 48][d-tile wid 16]
  acc[0] = (f32x4){0.f,0.f,0.f,0.f};
  acc[1] = (f32x4){0.f,0.f,0.f,0.f};
  acc[2] = (f32x4){0.f,0.f,0.f,0.f};

  const int rowin = 16*wid + lm;     // this lane's row within the 64-row unit

  // per-unit staging: lane holds row rowin, float cols {8lg..+7, 32+8lg..+7}
  auto process = [&](float4 c0, float4 c1, float4 c2, float4 c3,
                     unsigned short* aw, unsigned short* xw) {
    float ss = 0.f;
    ss = fmaf(c0.x,c0.x,ss); ss = fmaf(c0.y,c0.y,ss); ss = fmaf(c0.z,c0.z,ss); ss = fmaf(c0.w,c0.w,ss);
    ss = fmaf(c1.x,c1.x,ss); ss = fmaf(c1.y,c1.y,ss); ss = fmaf(c1.z,c1.z,ss); ss = fmaf(c1.w,c1.w,ss);
    ss = fmaf(c2.x,c2.x,ss); ss = fmaf(c2.y,c2.y,ss); ss = fmaf(c2.z,c2.z,ss); ss = fmaf(c2.w,c2.w,ss);
    ss = fmaf(c3.x,c3.x,ss); ss = fmaf(c3.y,c3.y,ss); ss = fmaf(c3.z,c3.z,ss); ss = fmaf(c3.w,c3.w,ss);
    ss += __shfl_xor(ss, 16);
    ss += __shfl_xor(ss, 32);
    float rn = rsqrtf(fmaxf(ss, 1e-24f));

    bf16x8 bh0, bl0, bh1, bl1;
    CVT1(c0.x,bh0,bl0,0) CVT1(c0.y,bh0,bl0,1) CVT1(c0.z,bh0,bl0,2) CVT1(c0.w,bh0,bl0,3)
    CVT1(c1.x,bh0,bl0,4) CVT1(c1.y,bh0,bl0,5) CVT1(c1.z,bh0,bl0,6) CVT1(c1.w,bh0,bl0,7)
    CVT1(c2.x,bh1,bl1,0) CVT1(c2.y,bh1,bl1,1) CVT1(c2.z,bh1,bl1,2) CVT1(c2.w,bh1,bl1,3)
    CVT1(c3.x,bh1,bl1,4) CVT1(c3.y,bh1,bl1,5) CVT1(c3.z,bh1,bl1,6) CVT1(c3.w,bh1,bl1,7)

    // cos GEMM: D[m=c][n=row] = cn . x (raw x; rn applied in softmax arg)
    f32x4 q0 = (f32x4){0,0,0,0}, q1 = (f32x4){0,0,0,0}, q2 = (f32x4){0,0,0,0};
    q0 = MFMA(cnf[0][0], bh0, q0); q0 = MFMA(cnf[0][1], bh1, q0);
    q0 = MFMA(cnf[0][0], bl0, q0); q0 = MFMA(cnf[0][1], bl1, q0);
    q1 = MFMA(cnf[1][0], bh0, q1); q1 = MFMA(cnf[1][1], bh1, q1);
    q1 = MFMA(cnf[1][0], bl0, q1); q1 = MFMA(cnf[1][1], bl1, q1);
    q2 = MFMA(cnf[2][0], bh0, q2); q2 = MFMA(cnf[2][1], bh1, q2);
    q2 = MFMA(cnf[2][0], bl0, q2); q2 = MFMA(cnf[2][1], bl1, q2);
    f32x4 q[3] = {q0, q1, q2};

    // softmax over c; lane holds c = 16ct+4lg+r for its row (n-col = lm)
    float e[3][4]; float psum = 0.f;
    #pragma unroll
    for (int ct = 0; ct < 3; ++ct)
      #pragma unroll
      for (int r = 0; r < 4; ++r) {
        int c = 16*ct + 4*lg + r;
        float ev = (c < C_) ? __expf(ALPHA_ * rn * q[ct][r]) : 0.f;
        e[ct][r] = ev; psum += ev;
      }
    psum += __shfl_xor(psum, 16);
    psum += __shfl_xor(psum, 32);
    float arn = rn / psum;               // (assign * rn) scale

    #pragma unroll
    for (int ct = 0; ct < 3; ++ct)
      #pragma unroll
      for (int r = 0; r < 4; ++r)
        aw[(16*ct + 4*lg + r)*PIT_ + rowin] = (unsigned short)bfbits(e[ct][r] * arn);
    #pragma unroll
    for (int j = 0; j < 8; ++j) {
      xw[(     8*lg + j)*PIT_ + rowin] = (unsigned short)bh0[j];   // xt[d][row]
      xw[(32 + 8*lg + j)*PIT_ + rowin] = (unsigned short)bh1[j];
    }
  };

  // ws GEMM over the unit's 64 rows for this wave's d-tile (d = 16*wid+lm)
  auto wsgemm = [&](const unsigned short* aw, const unsigned short* xw) {
    #pragma unroll
    for (int s = 0; s < 2; ++s) {                      // k = rows 32s..32s+31
      bf16x8 xf = ld_frag(&xw[(16*wid + lm)*PIT_ + 32*s + 8*lg]);
      bf16x8 a0 = ld_frag(&aw[( 0 + lm)*PIT_ + 32*s + 8*lg]);
      bf16x8 a1 = ld_frag(&aw[(16 + lm)*PIT_ + 32*s + 8*lg]);
      bf16x8 a2 = ld_frag(&aw[(32 + lm)*PIT_ + 32*s + 8*lg]);
      acc[0] = MFMA(a0, xf, acc[0]);
      acc[1] = MFMA(a1, xf, acc[1]);
      acc[2] = MFMA(a2, xf, acc[2]);
    }
  };

  // lane's global base: its row (16*wid+lm) of unit 0; units stride 64 rows
  const float* px = x + ((size_t)b*N_ + (size_t)nb*RPB_ + rowin)*D_ + lg*8;

  #define LOADU(P0,P1,P2,P3,U) { const float* p_ = px + (size_t)(U)*4096; \
    P0=*(const float4*)p_; P1=*(const float4*)(p_+4); P2=*(const float4*)(p_+32); P3=*(const float4*)(p_+36); }

  float4 A0,A1,A2,A3, B0,B1,B2,B3;
  LOADU(A0,A1,A2,A3, 0)
  LOADU(B0,B1,B2,B3, 1)

  #pragma unroll
  for (int u = 0; u < 8; u += 2) {
    process(A0,A1,A2,A3, aw0, xw0);          // unit u -> buf 0
    if (u < 6) LOADU(A0,A1,A2,A3, u+2)
    __syncthreads();                         // buf0 writes visible
    wsgemm(aw0, xw0);

    process(B0,B1,B2,B3, aw1, xw1);          // unit u+1 -> buf 1
    if (u < 6) LOADU(B0,B1,B2,B3, u+3)
    __syncthreads();                         // buf1 visible; also fences buf0
    wsgemm(aw1, xw1);                        //   reads before next buf0 write
  }
  #undef LOADU

  // ---- epilogue: disjoint output tiles -> plain stores, no reduction ----
  if (NPART == NB_) {
    float* wp = wsP + (size_t)blockIdx.x*(C_*D_) + 16*wid + lm;  // d = 16wid+lm
    #pragma unroll
    for (int ct = 0; ct < 3; ++ct)
      #pragma unroll
      for (int r = 0; r < 4; ++r) {
        int c = 16*ct + 4*lg + r;
        if (c < C_) wp[c*D_] = acc[ct][r];
      }
  } else {
    float* wp = wsP + (size_t)b*(C_*D_) + 16*wid + lm;
    #pragma unroll
    for (int ct = 0; ct < 3; ++ct)
      #pragma unroll
      for (int r = 0; r < 4; ++r) {
        int c = 16*ct + 4*lg + r;
        if (c < C_) atomicAdd(&wp[c*D_], acc[ct][r]);
      }
  }
}

// ---------------------------------------------------------------------------
// Reduce + finalize: grid = B_*FG_ (1024) x 256 threads; 4 k-quarters
// reduced via LDS (already at its HBM floor ~3 us). sp via identity;
// global norm analytic (all C_ rows unit-norm => ||flat|| = sqrt(C_)).
// ---------------------------------------------------------------------------
template<int NPART>
__global__ __launch_bounds__(256) void k_red1(
    const float* __restrict__ cent, const float* __restrict__ wsP,
    float* __restrict__ out)
{
  const int bc = blockIdx.x;
  const int b  = bc >> 5;        // / FG_
  const int c  = bc & 31;        // % FG_
  const int t  = threadIdx.x;
  const int d  = t & 63;
  const int kq = t >> 6;         // k-quarter

  __shared__ float pr[4][64];

  float s = 0.f;
  for (int k = kq; k < NPART; k += 4)
    s += wsP[((size_t)b*NPART + k)*(C_*D_) + c*D_ + d];
  pr[kq][d] = s;
  __syncthreads();

  if (t < 64) {
    s = pr[0][d] + pr[1][d] + pr[2][d] + pr[3][d];

    float cv = cent[d*C_ + c];
    float cs = cv*cv;
    #pragma unroll
    for (int off = 32; off; off >>= 1) cs += __shfl_xor(cs, off);
    float cn = cv * rsqrtf(fmaxf(cs, 1e-24f));

    float spv = cn * s;
    #pragma unroll
    for (int off = 32; off; off >>= 1) spv += __shfl_xor(spv, off);

    float v = s - cn * spv;
    float vs = v*v;
    #pragma unroll
    for (int off = 32; off; off >>= 1) vs += __shfl_xor(vs, off);

    const float rg = 0.16666666666666666f;   // 1/sqrt(C_)
    out[(size_t)bc*D_ + d] = v * rsqrtf(fmaxf(vs, 1e-24f)) * rg;
  }
}

extern "C" void kernel_launch(void* const* d_in, const int* in_sizes, int n_in,
                              void* d_out, int out_size, void* d_ws, size_t ws_size,
                              hipStream_t stream) {
  const float* x    = (const float*)d_in[0];
  const float* cent = (const float*)d_in[1];
  float* out = (float*)d_out;

  const size_t nblk = (size_t)B_ * NB_;                 // 1024
  const size_t need = nblk*(C_*D_) * sizeof(float);     // ~9.4 MB

  if (ws_size >= need) {
    float* wsP = (float*)d_ws;                          // [1024][2304]
    k_accum<NB_><<<B_*NB_, 256, 0, stream>>>(x, cent, wsP);
    k_red1<NB_><<<B_*FG_, 256, 0, stream>>>(cent, wsP, out);
  } else {                                              // atomic fallback
    float* wsA = (float*)d_ws;                          // [32][2304]
    hipMemsetAsync(d_ws, 0, (size_t)B_*(C_*D_)*sizeof(float), stream);
    k_accum<1><<<B_*NB_, 256, 0, stream>>>(x, cent, wsA);
    k_red1<1><<<B_*FG_, 256, 0, stream>>>(cent, wsA, out);
  }
}

// Round 16
// 36.184 us; speedup vs baseline: 2.3099x; 2.2159x over previous
//
#include <hip/hip_runtime.h>
#include <hip/hip_bf16.h>

#define B_     32
#define N_     16384
#define D_     64
#define C_     36
#define CP_    48     // padded cluster count (3 x 16 MFMA tiles)
#define FG_    32
#define ALPHA_ 10.0f
#define NB_    32     // n-blocks per batch -> grid 1024 = 4 blocks/CU
#define RPB_   (N_/NB_)   // 512 rows per block
#define PIT_   68         // LDS row pitch (elements): 136 B = 8B-aligned rows
                          // NOTE r15: PIT=70 fixes bank conflicts but flips the
                          // register allocator into a 64-VGPR spilling build
                          // (36 -> 80 us). Keep 68: allocator-stable point.

typedef __attribute__((ext_vector_type(8))) short bf16x8;
typedef __attribute__((ext_vector_type(4))) short bf16x4;
typedef __attribute__((ext_vector_type(4))) float f32x4;

#define MFMA(a,b,c) __builtin_amdgcn_mfma_f32_16x16x32_bf16(a,b,c,0,0,0)

// float -> bf16 bits via native conversion (v_cvt_pk_bf16_f32, RNE on gfx950).
__device__ __forceinline__ short bfbits(float v){
  __bf16 h = (__bf16)v;
  return __builtin_bit_cast(short, h);
}
__device__ __forceinline__ float bfval(short u){
  return __uint_as_float(((unsigned)(unsigned short)u) << 16);
}

// v -> hi bf16 (slot J of H) + residual lo bf16 (slot J of L)
#define CVT1(v, H, L, J) { short hb_ = bfbits(v); (H)[J] = hb_; \
  (L)[J] = bfbits((v) - bfval(hb_)); }

__device__ __forceinline__ bf16x8 ld_frag(const unsigned short* p){
  bf16x4 a = *(const bf16x4*)p;
  bf16x4 b = *(const bf16x4*)(p + 4);
  return __builtin_shufflevector(a, b, 0,1,2,3,4,5,6,7);
}

// ---------------------------------------------------------------------------
// Cooperative-block kernel (round-12 exact source — proven 36.2 us).
// grid = 1024 (32 batches x 32 n-blocks), block = 256 = 4 waves.
// Block processes 8 units of 64 rows; per unit each wave computes cos+softmax
// for its OWN 16 rows (row = 16*wid + lm) into a DOUBLE-BUFFERED shared
// asg/xt pair, then ws-GEMMs all 64 rows against its PRIVATE 16-wide d-tile
// (d = 16*wid + lm). One __syncthreads per unit. acc = 3 f32x4 (12 AGPRs).
// Codegen-stability ledger (DO NOT perturb without asm visibility):
//   r9  (256,4) bounds      -> 64-VGPR spill build, 55 us
//   r13 asm barrier+schedbar-> order-pinning regression, 40 us (m141)
//   r14 4-unit loop         -> 60-VGPR spill build, 84 us
//   r15 PIT 68->70          -> 64-VGPR spill build, 80 us
//   r10 device-scope fence  -> L2-flush serialization, 170 us
// self_product recovered in k_red1 via identity sp[c] = sum_d cn[d,c]*ws[d,c].
// ---------------------------------------------------------------------------
template<int NPART>
__global__ __launch_bounds__(256, 2) void k_accum(
    const float* __restrict__ x, const float* __restrict__ cent,
    float* __restrict__ wsP)
{
  const int t   = threadIdx.x;
  const int wid = t >> 6;
  const int l   = t & 63;
  const int lm  = l & 15;
  const int lg  = l >> 4;
  const int b   = blockIdx.x >> 5;
  const int nb  = blockIdx.x & 31;

  __shared__ float nrmc[C_];
  __shared__ __align__(16) unsigned short aw0[CP_*PIT_];  // asg buf 0  6528 B
  __shared__ __align__(16) unsigned short xw0[D_*PIT_];   // xt  buf 0  8704 B
  __shared__ __align__(16) unsigned short aw1[CP_*PIT_];  // asg buf 1
  __shared__ __align__(16) unsigned short xw1[D_*PIT_];   // xt  buf 1

  if (t < C_) {
    float ss = 0.f;
    for (int d = 0; d < D_; ++d) { float v = cent[d*C_ + t]; ss = fmaf(v, v, ss); }
    nrmc[t] = rsqrtf(fmaxf(ss, 1e-24f));
  }
  __syncthreads();

  // normalized-centroid A-fragments: A[m=c][k=d], c = 16*ct+lm, d = 32*s+8*lg+j
  bf16x8 cnf[3][2];
  #pragma unroll
  for (int ct = 0; ct < 3; ++ct) {
    #pragma unroll
    for (int s = 0; s < 2; ++s) {
      bf16x8 f;
      #pragma unroll
      for (int j = 0; j < 8; ++j) {
        int d = 32*s + 8*lg + j;
        int c = 16*ct + lm;
        float v = (c < C_) ? cent[d*C_ + c] * nrmc[c] : 0.f;
        f[j] = bfbits(v);
      }
      cnf[ct][s] = f;
    }
  }

  f32x4 acc[3];                      // wave's output: [c 48][d-tile wid 16]
  acc[0] = (f32x4){0.f,0.f,0.f,0.f};
  acc[1] = (f32x4){0.f,0.f,0.f,0.f};
  acc[2] = (f32x4){0.f,0.f,0.f,0.f};

  const int rowin = 16*wid + lm;     // this lane's row within the 64-row unit

  // per-unit staging: lane holds row rowin, float cols {8lg..+7, 32+8lg..+7}
  auto process = [&](float4 c0, float4 c1, float4 c2, float4 c3,
                     unsigned short* aw, unsigned short* xw) {
    float ss = 0.f;
    ss = fmaf(c0.x,c0.x,ss); ss = fmaf(c0.y,c0.y,ss); ss = fmaf(c0.z,c0.z,ss); ss = fmaf(c0.w,c0.w,ss);
    ss = fmaf(c1.x,c1.x,ss); ss = fmaf(c1.y,c1.y,ss); ss = fmaf(c1.z,c1.z,ss); ss = fmaf(c1.w,c1.w,ss);
    ss = fmaf(c2.x,c2.x,ss); ss = fmaf(c2.y,c2.y,ss); ss = fmaf(c2.z,c2.z,ss); ss = fmaf(c2.w,c2.w,ss);
    ss = fmaf(c3.x,c3.x,ss); ss = fmaf(c3.y,c3.y,ss); ss = fmaf(c3.z,c3.z,ss); ss = fmaf(c3.w,c3.w,ss);
    ss += __shfl_xor(ss, 16);
    ss += __shfl_xor(ss, 32);
    float rn = rsqrtf(fmaxf(ss, 1e-24f));

    bf16x8 bh0, bl0, bh1, bl1;
    CVT1(c0.x,bh0,bl0,0) CVT1(c0.y,bh0,bl0,1) CVT1(c0.z,bh0,bl0,2) CVT1(c0.w,bh0,bl0,3)
    CVT1(c1.x,bh0,bl0,4) CVT1(c1.y,bh0,bl0,5) CVT1(c1.z,bh0,bl0,6) CVT1(c1.w,bh0,bl0,7)
    CVT1(c2.x,bh1,bl1,0) CVT1(c2.y,bh1,bl1,1) CVT1(c2.z,bh1,bl1,2) CVT1(c2.w,bh1,bl1,3)
    CVT1(c3.x,bh1,bl1,4) CVT1(c3.y,bh1,bl1,5) CVT1(c3.z,bh1,bl1,6) CVT1(c3.w,bh1,bl1,7)

    // cos GEMM: D[m=c][n=row] = cn . x (raw x; rn applied in softmax arg)
    f32x4 q0 = (f32x4){0,0,0,0}, q1 = (f32x4){0,0,0,0}, q2 = (f32x4){0,0,0,0};
    q0 = MFMA(cnf[0][0], bh0, q0); q0 = MFMA(cnf[0][1], bh1, q0);
    q0 = MFMA(cnf[0][0], bl0, q0); q0 = MFMA(cnf[0][1], bl1, q0);
    q1 = MFMA(cnf[1][0], bh0, q1); q1 = MFMA(cnf[1][1], bh1, q1);
    q1 = MFMA(cnf[1][0], bl0, q1); q1 = MFMA(cnf[1][1], bl1, q1);
    q2 = MFMA(cnf[2][0], bh0, q2); q2 = MFMA(cnf[2][1], bh1, q2);
    q2 = MFMA(cnf[2][0], bl0, q2); q2 = MFMA(cnf[2][1], bl1, q2);
    f32x4 q[3] = {q0, q1, q2};

    // softmax over c; lane holds c = 16ct+4lg+r for its row (n-col = lm)
    float e[3][4]; float psum = 0.f;
    #pragma unroll
    for (int ct = 0; ct < 3; ++ct)
      #pragma unroll
      for (int r = 0; r < 4; ++r) {
        int c = 16*ct + 4*lg + r;
        float ev = (c < C_) ? __expf(ALPHA_ * rn * q[ct][r]) : 0.f;
        e[ct][r] = ev; psum += ev;
      }
    psum += __shfl_xor(psum, 16);
    psum += __shfl_xor(psum, 32);
    float arn = rn / psum;               // (assign * rn) scale

    #pragma unroll
    for (int ct = 0; ct < 3; ++ct)
      #pragma unroll
      for (int r = 0; r < 4; ++r)
        aw[(16*ct + 4*lg + r)*PIT_ + rowin] = (unsigned short)bfbits(e[ct][r] * arn);
    #pragma unroll
    for (int j = 0; j < 8; ++j) {
      xw[(     8*lg + j)*PIT_ + rowin] = (unsigned short)bh0[j];   // xt[d][row]
      xw[(32 + 8*lg + j)*PIT_ + rowin] = (unsigned short)bh1[j];
    }
  };

  // ws GEMM over the unit's 64 rows for this wave's d-tile (d = 16*wid+lm)
  auto wsgemm = [&](const unsigned short* aw, const unsigned short* xw) {
    #pragma unroll
    for (int s = 0; s < 2; ++s) {                      // k = rows 32s..32s+31
      bf16x8 xf = ld_frag(&xw[(16*wid + lm)*PIT_ + 32*s + 8*lg]);
      bf16x8 a0 = ld_frag(&aw[( 0 + lm)*PIT_ + 32*s + 8*lg]);
      bf16x8 a1 = ld_frag(&aw[(16 + lm)*PIT_ + 32*s + 8*lg]);
      bf16x8 a2 = ld_frag(&aw[(32 + lm)*PIT_ + 32*s + 8*lg]);
      acc[0] = MFMA(a0, xf, acc[0]);
      acc[1] = MFMA(a1, xf, acc[1]);
      acc[2] = MFMA(a2, xf, acc[2]);
    }
  };

  // lane's global base: its row (16*wid+lm) of unit 0; units stride 64 rows
  const float* px = x + ((size_t)b*N_ + (size_t)nb*RPB_ + rowin)*D_ + lg*8;

  #define LOADU(P0,P1,P2,P3,U) { const float* p_ = px + (size_t)(U)*4096; \
    P0=*(const float4*)p_; P1=*(const float4*)(p_+4); P2=*(const float4*)(p_+32); P3=*(const float4*)(p_+36); }

  float4 A0,A1,A2,A3, B0,B1,B2,B3;
  LOADU(A0,A1,A2,A3, 0)
  LOADU(B0,B1,B2,B3, 1)

  #pragma unroll
  for (int u = 0; u < 8; u += 2) {
    process(A0,A1,A2,A3, aw0, xw0);          // unit u -> buf 0
    if (u < 6) LOADU(A0,A1,A2,A3, u+2)
    __syncthreads();                         // buf0 writes visible
    wsgemm(aw0, xw0);

    process(B0,B1,B2,B3, aw1, xw1);          // unit u+1 -> buf 1
    if (u < 6) LOADU(B0,B1,B2,B3, u+3)
    __syncthreads();                         // buf1 visible; also fences buf0
    wsgemm(aw1, xw1);                        //   reads before next buf0 write
  }
  #undef LOADU

  // ---- epilogue: disjoint output tiles -> plain stores, no reduction ----
  if (NPART == NB_) {
    float* wp = wsP + (size_t)blockIdx.x*(C_*D_) + 16*wid + lm;  // d = 16wid+lm
    #pragma unroll
    for (int ct = 0; ct < 3; ++ct)
      #pragma unroll
      for (int r = 0; r < 4; ++r) {
        int c = 16*ct + 4*lg + r;
        if (c < C_) wp[c*D_] = acc[ct][r];
      }
  } else {
    float* wp = wsP + (size_t)b*(C_*D_) + 16*wid + lm;
    #pragma unroll
    for (int ct = 0; ct < 3; ++ct)
      #pragma unroll
      for (int r = 0; r < 4; ++r) {
        int c = 16*ct + 4*lg + r;
        if (c < C_) atomicAdd(&wp[c*D_], acc[ct][r]);
      }
  }
}

// ---------------------------------------------------------------------------
// Reduce + finalize: grid = B_*FG_ (1024) x 256 threads; 4 k-quarters
// reduced via LDS (already at its HBM floor ~3 us). sp via identity;
// global norm analytic (all C_ rows unit-norm => ||flat|| = sqrt(C_)).
// ---------------------------------------------------------------------------
template<int NPART>
__global__ __launch_bounds__(256) void k_red1(
    const float* __restrict__ cent, const float* __restrict__ wsP,
    float* __restrict__ out)
{
  const int bc = blockIdx.x;
  const int b  = bc >> 5;        // / FG_
  const int c  = bc & 31;        // % FG_
  const int t  = threadIdx.x;
  const int d  = t & 63;
  const int kq = t >> 6;         // k-quarter

  __shared__ float pr[4][64];

  float s = 0.f;
  for (int k = kq; k < NPART; k += 4)
    s += wsP[((size_t)b*NPART + k)*(C_*D_) + c*D_ + d];
  pr[kq][d] = s;
  __syncthreads();

  if (t < 64) {
    s = pr[0][d] + pr[1][d] + pr[2][d] + pr[3][d];

    float cv = cent[d*C_ + c];
    float cs = cv*cv;
    #pragma unroll
    for (int off = 32; off; off >>= 1) cs += __shfl_xor(cs, off);
    float cn = cv * rsqrtf(fmaxf(cs, 1e-24f));

    float spv = cn * s;
    #pragma unroll
    for (int off = 32; off; off >>= 1) spv += __shfl_xor(spv, off);

    float v = s - cn * spv;
    float vs = v*v;
    #pragma unroll
    for (int off = 32; off; off >>= 1) vs += __shfl_xor(vs, off);

    const float rg = 0.16666666666666666f;   // 1/sqrt(C_)
    out[(size_t)bc*D_ + d] = v * rsqrtf(fmaxf(vs, 1e-24f)) * rg;
  }
}

extern "C" void kernel_launch(void* const* d_in, const int* in_sizes, int n_in,
                              void* d_out, int out_size, void* d_ws, size_t ws_size,
                              hipStream_t stream) {
  const float* x    = (const float*)d_in[0];
  const float* cent = (const float*)d_in[1];
  float* out = (float*)d_out;

  const size_t nblk = (size_t)B_ * NB_;                 // 1024
  const size_t need = nblk*(C_*D_) * sizeof(float);     // ~9.4 MB

  if (ws_size >= need) {
    float* wsP = (float*)d_ws;                          // [1024][2304]
    k_accum<NB_><<<B_*NB_, 256, 0, stream>>>(x, cent, wsP);
    k_red1<NB_><<<B_*FG_, 256, 0, stream>>>(cent, wsP, out);
  } else {                                              // atomic fallback
    float* wsA = (float*)d_ws;                          // [32][2304]
    hipMemsetAsync(d_ws, 0, (size_t)B_*(C_*D_)*sizeof(float), stream);
    k_accum<1><<<B_*NB_, 256, 0, stream>>>(x, cent, wsA);
    k_red1<1><<<B_*FG_, 256, 0, stream>>>(cent, wsA, out);
  }
}